// Round 3
// baseline (182.653 us; speedup 1.0000x reference)
//
#include <hip/hip_runtime.h>

typedef __attribute__((ext_vector_type(4))) float f32x4;
typedef __attribute__((ext_vector_type(8))) short s16x8;
typedef unsigned short u16;

#define DEVI __device__ __forceinline__

// fp32 -> bf16 round-to-nearest-even
DEVI u16 f2bf(float f) {
    union { float f; unsigned int u; } v; v.f = f;
    unsigned int r = v.u + 0x7FFFu + ((v.u >> 16) & 1u);
    return (u16)(r >> 16);
}

typedef __attribute__((address_space(1))) void gv_t;   // global
typedef __attribute__((address_space(3))) void sv_t;   // LDS

#define GLOAD16(SRC, DST) __builtin_amdgcn_global_load_lds( \
    (gv_t*)(SRC), (sv_t*)(DST), 16, 0, 0)

DEVI f32x4 mfma_bf16(s16x8 a, s16x8 b, f32x4 c) {
    return __builtin_amdgcn_mfma_f32_16x16x32_bf16(a, b, c, 0, 0, 0);
}

// ---------------------------------------------------------------------------
// fp32 -> bf16: x, wq, wk, wv (pre-QKV-GEMM pass)
// ---------------------------------------------------------------------------
__global__ void cvt1_kernel(
    const float* __restrict__ x,  const float* __restrict__ wq, const float* __restrict__ wk,
    const float* __restrict__ wv,
    u16* __restrict__ xb, u16* __restrict__ wqb, u16* __restrict__ wkb,
    u16* __restrict__ wvb)
{
    int id = blockIdx.x * 256 + threadIdx.x;   // 0 .. 4423680-1 (f32x4 units)
    const float* s; u16* d; int off;
    if      (id < 737280)  { s = x;  d = xb;  off = id; }
    else if (id < 3686400) { s = wq; d = wqb; off = id - 737280; }
    else if (id < 4055040) { s = wk; d = wkb; off = id - 3686400; }
    else                   { s = wv; d = wvb; off = id - 4055040; }
    f32x4 v = *(const f32x4*)(s + (size_t)off * 4);
    union { u16 u[4]; unsigned long long ll; } o;
    #pragma unroll
    for (int j = 0; j < 4; ++j) o.u[j] = f2bf(v[j]);
    *(unsigned long long*)(d + (size_t)off * 4) = o.ll;
}

// fp32 -> bf16: wo only (runs after rope; wob overlays dead qkv partials)
__global__ void cvt_wo_kernel(const float* __restrict__ wo, u16* __restrict__ wob)
{
    int id = blockIdx.x * 256 + threadIdx.x;   // 0 .. 2949120-1
    f32x4 v = *(const f32x4*)(wo + (size_t)id * 4);
    union { u16 u[4]; unsigned long long ll; } o;
    #pragma unroll
    for (int j = 0; j < 4; ++j) o.u[j] = f2bf(v[j]);
    *(unsigned long long*)(wob + (size_t)id * 4) = o.ll;
}

// ---------------------------------------------------------------------------
// NT GEMM, split-K, single-buffered m97 structure (2 barriers / K-step;
// pipelining comes from 4-5 co-resident blocks/CU).
// C_part[z] = A[M][K](bf16) * W[n][K](bf16)^T   (fp32 partials, no bias)
// 128x128 tile, BK=64, 4 waves of 64x64, 16x16x32 MFMA, gload_lds width 16,
// XOR chunk swizzle. XCD-aware block mapping: grid.x = ntiles_padded*8;
// consecutive blocks on one XCD share the same weight stripe (8 M-tiles).
// ---------------------------------------------------------------------------
__global__ __launch_bounds__(256, 5) void gemm_bf16nt(
    const u16* __restrict__ A, int lda, int kit, int ntot,
    const u16* __restrict__ W0, int t0, int n0, int c0,
    const u16* __restrict__ W1, int t1, int n1, int c1,
    const u16* __restrict__ W2, int t2, int n2, int c2,
    float* __restrict__ C, int ldc, long long cstride)
{
    __shared__ u16 Als[128 * 64];
    __shared__ u16 Bls[128 * 64];

    // XCD swizzle: lin%8 = XCD (round-robin hypothesis). XCD c processes
    // nb = c, c+8, ... each as a run of 8 consecutive M-tiles -> weight
    // stripe stays in that XCD's L2 across its 8 M-tile readers.
    const int lin = blockIdx.x;
    const int xc  = lin & 7;
    const int mm  = lin >> 3;
    const int nbl = xc + 8 * (mm >> 3);
    const int yt  = mm & 7;
    if (nbl >= ntot) return;

    const int tid  = threadIdx.x;
    const int lane = tid & 63;
    const int wid  = tid >> 6;
    const int li   = lane & 15;
    const int lg   = lane >> 4;
    const int m0   = yt * 128;

    const u16* W; int nt0, nsz, cb;
    if (nbl < t0)           { W = W0; nt0 = nbl * 128;             nsz = n0; cb = c0; }
    else if (nbl < t0 + t1) { W = W1; nt0 = (nbl - t0) * 128;      nsz = n1; cb = c1; }
    else                    { W = W2; nt0 = (nbl - t0 - t1) * 128; nsz = n2; cb = c2; }

    const int z  = blockIdx.z;
    const int S  = gridDim.z;
    const int it0 = (z * kit) / S;
    const int it1 = ((z + 1) * kit) / S;
    float* Cp = C + (long long)z * cstride;

    const int wm = (wid >> 1) * 64;
    const int wn = (wid & 1) * 64;

    f32x4 acc[4][4];
    #pragma unroll
    for (int mi = 0; mi < 4; ++mi)
        #pragma unroll
        for (int ni = 0; ni < 4; ++ni)
            acc[mi][ni] = (f32x4){0.f, 0.f, 0.f, 0.f};

    const int srow = tid >> 3;                 // 0..31
    const int slc  = (tid & 7) ^ (srow & 7);   // inverse-swizzled source chunk

    for (int it = it0; it < it1; ++it) {
        const int k0 = it * 64;
        #pragma unroll
        for (int s_ = 0; s_ < 4; ++s_) {
            const u16* sa = A + (size_t)(m0 + s_ * 32 + srow) * lda + k0 + slc * 8;
            GLOAD16(sa, &Als[(s_ * 256 + wid * 64) * 8]);
        }
        #pragma unroll
        for (int s_ = 0; s_ < 4; ++s_) {
            int wr = nt0 + s_ * 32 + srow;
            if (wr > nsz - 1) wr = nsz - 1;    // ragged-N clamp (stores guarded)
            const u16* sb = W + (size_t)wr * lda + k0 + slc * 8;
            GLOAD16(sb, &Bls[(s_ * 256 + wid * 64) * 8]);
        }
        __syncthreads();

        s16x8 af[4][2], bfv[4][2];
        #pragma unroll
        for (int mi = 0; mi < 4; ++mi)
            #pragma unroll
            for (int kc = 0; kc < 2; ++kc) {
                int row = wm + mi * 16 + li;
                int ch  = (kc * 4 + lg) ^ (row & 7);
                af[mi][kc] = *(const s16x8*)&Als[row * 64 + ch * 8];
            }
        #pragma unroll
        for (int ni = 0; ni < 4; ++ni)
            #pragma unroll
            for (int kc = 0; kc < 2; ++kc) {
                int row = wn + ni * 16 + li;
                int ch  = (kc * 4 + lg) ^ (row & 7);
                bfv[ni][kc] = *(const s16x8*)&Bls[row * 64 + ch * 8];
            }
        #pragma unroll
        for (int mi = 0; mi < 4; ++mi)
            #pragma unroll
            for (int ni = 0; ni < 4; ++ni)
                #pragma unroll
                for (int kc = 0; kc < 2; ++kc)
                    acc[mi][ni] = mfma_bf16(af[mi][kc], bfv[ni][kc], acc[mi][ni]);
        __syncthreads();
    }

    #pragma unroll
    for (int ni = 0; ni < 4; ++ni) {
        int colr = nt0 + wn + ni * 16 + li;
        if (colr < nsz) {
            #pragma unroll
            for (int mi = 0; mi < 4; ++mi)
                #pragma unroll
                for (int r = 0; r < 4; ++r) {
                    int row = m0 + wm + mi * 16 + lg * 4 + r;
                    Cp[(size_t)row * ldc + cb + colr] = acc[mi][ni][r];
                }
        }
    }
}

// ---------------------------------------------------------------------------
// RoPE + bias + bf16 convert from 3 split-K partials.
// ---------------------------------------------------------------------------
__global__ void rope_kernel(const float* __restrict__ qkvp,
                            const float* __restrict__ qb, const float* __restrict__ kb,
                            const float* __restrict__ vb,
                            u16* __restrict__ qo, u16* __restrict__ ko, u16* __restrict__ vo)
{
    const long long PST = 1024LL * 5120;
    int id = blockIdx.x * 256 + threadIdx.x;   // 1024 * 2560
    int s  = id / 2560;
    int r  = id % 2560;
    const float* r0 = qkvp + (size_t)s * 5120;
    if (r < 2304) {
        bool isq = r < 2048;
        int rr   = isq ? r : r - 2048;
        int hh   = rr >> 5;
        int d    = rr & 31;
        int col  = (isq ? 0 : 4096) + hh * 64 + d;
        int bcol = isq ? col : col - 4096;
        const float* bias = isq ? qb : kb;
        float t1 = r0[col]            + r0[col + PST]      + r0[col + 2 * PST]      + bias[bcol];
        float t2 = r0[col + 32]       + r0[col + 32 + PST] + r0[col + 32 + 2 * PST] + bias[bcol + 32];
        // inv_freq = 150000^(-d/32) = exp2(-d * log2(150000)/32)
        float ang = (float)s * exp2f((float)d * -0.5373314f);
        float sn, cs;
        sincosf(ang, &sn, &cs);
        float sc = isq ? 0.125f : 1.0f;    // fold score scale HD^-0.5 into q
        float o1 = (t1 * cs - t2 * sn) * sc;
        float o2 = (t1 * sn + t2 * cs) * sc;
        u16* dst = isq ? qo : ko;
        int ldd  = isq ? 4096 : 512;
        dst[(size_t)s * ldd + bcol]      = f2bf(o1);
        dst[(size_t)s * ldd + bcol + 32] = f2bf(o2);
    } else {
        int e = (r - 2304) * 2;
        int c0 = 4608 + e;
        float v0 = r0[c0]     + r0[c0 + PST]     + r0[c0 + 2 * PST]     + vb[e];
        float v1 = r0[c0 + 1] + r0[c0 + 1 + PST] + r0[c0 + 1 + 2 * PST] + vb[e + 1];
        vo[(size_t)s * 512 + e]     = f2bf(v0);
        vo[(size_t)s * 512 + e + 1] = f2bf(v1);
    }
}

// ---------------------------------------------------------------------------
// out = sum of 5 split-K partials + bias (fp32)
// ---------------------------------------------------------------------------
__global__ void reduce_out_kernel(const float* __restrict__ parts,
                                  const float* __restrict__ bias,
                                  float* __restrict__ out)
{
    int id = blockIdx.x * 256 + threadIdx.x;      // f32x4 index, 0..737279
    const long long stride = 1024LL * 2880 / 4;   // in f32x4 units
    f32x4 s = ((const f32x4*)parts)[id];
    #pragma unroll
    for (int p = 1; p < 5; ++p) s += ((const f32x4*)parts)[id + p * stride];
    int cb = (id % 720) * 4;
    f32x4 b = *(const f32x4*)(bias + cb);
    ((f32x4*)out)[id] = s + b;
}

// ---------------------------------------------------------------------------
// Sliding-window GQA attention with sinks (unchanged, proven).
// ---------------------------------------------------------------------------
__global__ __launch_bounds__(256, 2) void attn_kernel(
    const u16* __restrict__ Q, const u16* __restrict__ Kb, const u16* __restrict__ Vb,
    const float* __restrict__ sinks, u16* __restrict__ Ob)
{
    __shared__ u16 Kls[64 * 64];
    __shared__ u16 Pls[4][16 * 72];

    const int h    = blockIdx.x;
    const int qblk = blockIdx.y;
    const int kvh  = h >> 3;
    const int tid  = threadIdx.x;
    const int lane = tid & 63;
    const int w    = tid >> 6;
    const int li   = lane & 15;
    const int lg   = lane >> 4;
    const int qw   = qblk * 64 + w * 16;

    s16x8 aq[2];
    {
        const u16* qrow = Q + ((size_t)(qw + li) * 64 + h) * 64 + lg * 8;
        aq[0] = *(const s16x8*)(qrow);
        aq[1] = *(const s16x8*)(qrow + 32);
    }

    const float snk = sinks[h];
    float m_run[4], l_run[4];
    f32x4 oacc[4];
    #pragma unroll
    for (int r = 0; r < 4; ++r) { m_run[r] = snk; l_run[r] = 1.0f; }
    #pragma unroll
    for (int ni = 0; ni < 4; ++ni) oacc[ni] = (f32x4){0.f, 0.f, 0.f, 0.f};

    const int srow = tid >> 3;
    const int slc  = (tid & 7) ^ (srow & 7);

    for (int t = 0; t < 3; ++t) {
        int jt = qblk - 2 + t;
        if (jt < 0) continue;
        int j0 = jt * 64;

        #pragma unroll
        for (int it = 0; it < 2; ++it) {
            const u16* src = Kb + ((size_t)(j0 + it * 32 + srow) * 8 + kvh) * 64 + slc * 8;
            GLOAD16(src, &Kls[(it * 256 + w * 64) * 8]);
        }
        __syncthreads();

        f32x4 sc[4];
        #pragma unroll
        for (int nf = 0; nf < 4; ++nf) {
            sc[nf] = (f32x4){0.f, 0.f, 0.f, 0.f};
            #pragma unroll
            for (int kc = 0; kc < 2; ++kc) {
                int row = nf * 16 + li;
                int ch  = (kc * 4 + lg) ^ (row & 7);
                s16x8 bk = *(const s16x8*)&Kls[row * 64 + ch * 8];
                sc[nf] = mfma_bf16(aq[kc], bk, sc[nf]);
            }
        }

        #pragma unroll
        for (int r = 0; r < 4; ++r) {
            const int qg = qw + lg * 4 + r;
            float mx = -1e30f;
            #pragma unroll
            for (int nf = 0; nf < 4; ++nf) {
                int jg = j0 + nf * 16 + li;
                bool ok = (jg <= qg) && (qg - jg < 128);
                float v = ok ? sc[nf][r] : -1e30f;
                sc[nf][r] = v;
                mx = fmaxf(mx, v);
            }
            #pragma unroll
            for (int off = 1; off < 16; off <<= 1)
                mx = fmaxf(mx, __shfl_xor(mx, off));
            float mnew = fmaxf(m_run[r], mx);
            float corr = __expf(m_run[r] - mnew);
            m_run[r] = mnew;
            float rs = 0.f;
            #pragma unroll
            for (int nf = 0; nf < 4; ++nf) {
                float p = __expf(sc[nf][r] - mnew);
                rs += p;
                Pls[w][(lg * 4 + r) * 72 + nf * 16 + li] = f2bf(p);
            }
            #pragma unroll
            for (int off = 1; off < 16; off <<= 1)
                rs += __shfl_xor(rs, off);
            l_run[r] = l_run[r] * corr + rs;
            #pragma unroll
            for (int ni = 0; ni < 4; ++ni) oacc[ni][r] *= corr;
        }
        __syncthreads();   // all K reads done; P writes drained

        #pragma unroll
        for (int kc = 0; kc < 2; ++kc) {
            s16x8 pa = *(const s16x8*)&Pls[w][li * 72 + kc * 32 + lg * 8];
            #pragma unroll
            for (int ni = 0; ni < 4; ++ni) {
                const u16* vsrc = Vb + ((size_t)(j0 + kc * 32 + lg * 8) * 8 + kvh) * 64 + ni * 16 + li;
                s16x8 bv;
                #pragma unroll
                for (int i = 0; i < 8; ++i) bv[i] = (short)vsrc[(size_t)i * 512];
                oacc[ni] = mfma_bf16(pa, bv, oacc[ni]);
            }
        }
    }

    #pragma unroll
    for (int r = 0; r < 4; ++r) {
        float inv = 1.0f / l_run[r];
        #pragma unroll
        for (int ni = 0; ni < 4; ++ni)
            Ob[((size_t)(qw + lg * 4 + r) * 64 + h) * 64 + ni * 16 + li] = f2bf(oacc[ni][r] * inv);
    }
}

// ---------------------------------------------------------------------------
extern "C" void kernel_launch(void* const* d_in, const int* in_sizes, int n_in,
                              void* d_out, int out_size, void* d_ws, size_t ws_size,
                              hipStream_t stream)
{
    const float* x     = (const float*)d_in[0];
    const float* wq_w  = (const float*)d_in[1];
    const float* wq_b  = (const float*)d_in[2];
    const float* wk_w  = (const float*)d_in[3];
    const float* wk_b  = (const float*)d_in[4];
    const float* wv_w  = (const float*)d_in[5];
    const float* wv_b  = (const float*)d_in[6];
    const float* wo_w  = (const float*)d_in[7];
    const float* wo_b  = (const float*)d_in[8];
    const float* sinks = (const float*)d_in[9];

    char* ws = (char*)d_ws;
    // Lifetimes / overlays (total 117,964,800 B <= proven-available ws):
    //   [0, 35,389,440)  cvt1 out: xb|wqb|wkb|wvb        (cvt1 -> gemm1)
    //        after rope overlays: qr@0 | kr | vbf | attb  (rope -> gemm2)
    //   [35,389,440, 98,304,000)  qkvp 3 partials         (gemm1 -> rope)
    //        after rope overlays: wob@35,389,440          (cvt_wo -> gemm2)
    //   [58,982,400, 117,964,800) oprt 5 partials         (gemm2 -> reduce)
    u16*   xb   = (u16*)  (ws + 0);
    u16*   wqb  = (u16*)  (ws + 5898240ULL);
    u16*   wkb  = (u16*)  (ws + 29491200ULL);
    u16*   wvb  = (u16*)  (ws + 32440320ULL);
    float* qkvp = (float*)(ws + 35389440ULL);      // 3 partials, stride 1024*5120
    u16*   qr   = (u16*)  (ws + 0);
    u16*   kr   = (u16*)  (ws + 8388608ULL);
    u16*   vbf  = (u16*)  (ws + 9437184ULL);
    u16*   attb = (u16*)  (ws + 10485760ULL);
    u16*   wob  = (u16*)  (ws + 35389440ULL);
    float* oprt = (float*)(ws + 58982400ULL);      // 5 partials, stride 1024*2880

    (void)in_sizes; (void)n_in; (void)out_size; (void)ws_size;

    // 1) bf16 conversions (x, wq, wk, wv)
    cvt1_kernel<<<17280, 256, 0, stream>>>(x, wq_w, wk_w, wv_w, xb, wqb, wkb, wvb);
    // 2) fused QKV projection, split-K=3 -> 3 fp32 partials [1024][5120]
    //    grid.x = 40 N-tiles * 8 M-tiles (XCD-swizzled in kernel)
    gemm_bf16nt<<<dim3(320, 1, 3), 256, 0, stream>>>(xb, 2880, 45, 40,
        wqb, 32, 4096, 0,
        wkb, 4, 512, 4096,
        wvb, 4, 512, 4608,
        qkvp, 5120, 1024LL * 5120);
    // 3) RoPE + partial-sum + bias + convert (q pre-scaled by 0.125)
    rope_kernel<<<10240, 256, 0, stream>>>(qkvp, wq_b, wk_b, wv_b, qr, kr, vbf);
    // 4) wo -> bf16 (overlays dead qkv partials)
    cvt_wo_kernel<<<11520, 256, 0, stream>>>(wo_w, wob);
    // 5) attention -> attb bf16 [1024][4096]
    attn_kernel<<<dim3(64, 16), 256, 0, stream>>>(qr, kr, vbf, sinks, attb);
    // 6) output projection, split-K=5 -> 5 fp32 partials [1024][2880]
    //    N-tiles = 23 padded to 24; 8 dead blocks per z exit early
    gemm_bf16nt<<<dim3(192, 1, 5), 256, 0, stream>>>(attb, 4096, 64, 23,
        wob, 23, 2880, 0,
        wob, 0, 0, 0,
        wob, 0, 0, 0,
        oprt, 2880, 1024LL * 2880);
    // 7) reduce partials + bias -> d_out fp32 [1024][2880]
    reduce_out_kernel<<<2880, 256, 0, stream>>>(oprt, wo_b, (float*)d_out);
}

// Round 4
// 140.099 us; speedup vs baseline: 1.3037x; 1.3037x over previous
//
#include <hip/hip_runtime.h>

typedef __attribute__((ext_vector_type(4))) float f32x4;
typedef __attribute__((ext_vector_type(8))) short s16x8;
typedef unsigned short u16;

#define DEVI __device__ __forceinline__

// fp32 -> bf16 round-to-nearest-even
DEVI u16 f2bf(float f) {
    union { float f; unsigned int u; } v; v.f = f;
    unsigned int r = v.u + 0x7FFFu + ((v.u >> 16) & 1u);
    return (u16)(r >> 16);
}
DEVI float bf2f(u16 b) {
    union { unsigned int u; float f; } v; v.u = ((unsigned int)b) << 16;
    return v.f;
}

typedef __attribute__((address_space(1))) void gv_t;   // global
typedef __attribute__((address_space(3))) void sv_t;   // LDS

#define GLOAD16(SRC, DST) __builtin_amdgcn_global_load_lds( \
    (gv_t*)(SRC), (sv_t*)(DST), 16, 0, 0)

DEVI f32x4 mfma_bf16(s16x8 a, s16x8 b, f32x4 c) {
    return __builtin_amdgcn_mfma_f32_16x16x32_bf16(a, b, c, 0, 0, 0);
}

// ---------------------------------------------------------------------------
// fp32 -> bf16: x, wq, wk, wv (pre-QKV-GEMM pass)
// ---------------------------------------------------------------------------
__global__ void cvt1_kernel(
    const float* __restrict__ x,  const float* __restrict__ wq, const float* __restrict__ wk,
    const float* __restrict__ wv,
    u16* __restrict__ xb, u16* __restrict__ wqb, u16* __restrict__ wkb,
    u16* __restrict__ wvb)
{
    int id = blockIdx.x * 256 + threadIdx.x;   // 0 .. 4423680-1 (f32x4 units)
    const float* s; u16* d; int off;
    if      (id < 737280)  { s = x;  d = xb;  off = id; }
    else if (id < 3686400) { s = wq; d = wqb; off = id - 737280; }
    else if (id < 4055040) { s = wk; d = wkb; off = id - 3686400; }
    else                   { s = wv; d = wvb; off = id - 4055040; }
    f32x4 v = *(const f32x4*)(s + (size_t)off * 4);
    union { u16 u[4]; unsigned long long ll; } o;
    #pragma unroll
    for (int j = 0; j < 4; ++j) o.u[j] = f2bf(v[j]);
    *(unsigned long long*)(d + (size_t)off * 4) = o.ll;
}

// fp32 -> bf16: wo only (runs after rope; wob overlays dead qkv partials)
__global__ void cvt_wo_kernel(const float* __restrict__ wo, u16* __restrict__ wob)
{
    int id = blockIdx.x * 256 + threadIdx.x;   // 0 .. 2949120-1
    f32x4 v = *(const f32x4*)(wo + (size_t)id * 4);
    union { u16 u[4]; unsigned long long ll; } o;
    #pragma unroll
    for (int j = 0; j < 4; ++j) o.u[j] = f2bf(v[j]);
    *(unsigned long long*)(wob + (size_t)id * 4) = o.ll;
}

// ---------------------------------------------------------------------------
// NT GEMM, split-K, DEPTH-2 COUNTED-VMCNT PIPELINE (T3/T4 minimum form):
// raw s_barrier + s_waitcnt vmcnt(8) -- loads for tile t+2 stay in flight
// across two full compute phases; vmcnt never drains to 0 in the main loop.
// C_part[z] = A[M][K](bf16) * W[n][K](bf16)^T  -> bf16 partials (no bias).
// 128x128 tile, BK=64, 4 waves of 64x64, 16x16x32 MFMA, gload_lds width 16,
// XOR chunk swizzle, XCD-aware block mapping.
// ---------------------------------------------------------------------------
__global__ __launch_bounds__(256, 2) void gemm_bf16nt(
    const u16* __restrict__ A, int lda, int kit, int ntot,
    const u16* __restrict__ W0, int t0, int n0, int c0,
    const u16* __restrict__ W1, int t1, int n1, int c1,
    const u16* __restrict__ W2, int t2, int n2, int c2,
    u16* __restrict__ C, int ldc, long long cstride)
{
    __shared__ u16 Als[2][128 * 64];
    __shared__ u16 Bls[2][128 * 64];

    const int lin = blockIdx.x;
    const int xc  = lin & 7;
    const int mm  = lin >> 3;
    const int nbl = xc + 8 * (mm >> 3);
    const int yt  = mm & 7;
    if (nbl >= ntot) return;   // uniform per block; no barriers executed

    const int tid  = threadIdx.x;
    const int lane = tid & 63;
    const int wid  = tid >> 6;
    const int li   = lane & 15;
    const int lg   = lane >> 4;
    const int m0   = yt * 128;

    const u16* W; int nt0, nsz, cb;
    if (nbl < t0)           { W = W0; nt0 = nbl * 128;             nsz = n0; cb = c0; }
    else if (nbl < t0 + t1) { W = W1; nt0 = (nbl - t0) * 128;      nsz = n1; cb = c1; }
    else                    { W = W2; nt0 = (nbl - t0 - t1) * 128; nsz = n2; cb = c2; }

    const int z  = blockIdx.z;
    const int S  = gridDim.z;
    const int it0 = (z * kit) / S;
    const int it1 = ((z + 1) * kit) / S;    // always >= it0 + 12 here
    u16* Cp = C + (long long)z * cstride;

    const int wm = (wid >> 1) * 64;
    const int wn = (wid & 1) * 64;

    f32x4 acc[4][4];
    #pragma unroll
    for (int mi = 0; mi < 4; ++mi)
        #pragma unroll
        for (int ni = 0; ni < 4; ++ni)
            acc[mi][ni] = (f32x4){0.f, 0.f, 0.f, 0.f};

    const int srow = tid >> 3;                 // 0..31
    const int slc  = (tid & 7) ^ (srow & 7);   // inverse-swizzled source chunk

    // 8 gload_lds per thread per tile (4 A + 4 B)
#define STAGE(BUF, IT)                                                          \
    do {                                                                        \
        int k0_ = (IT) * 64;                                                    \
        _Pragma("unroll")                                                       \
        for (int s_ = 0; s_ < 4; ++s_) {                                        \
            const u16* sa_ = A + (size_t)(m0 + s_ * 32 + srow) * lda + k0_ + slc * 8; \
            GLOAD16(sa_, &Als[BUF][(s_ * 256 + wid * 64) * 8]);                 \
        }                                                                       \
        _Pragma("unroll")                                                       \
        for (int s_ = 0; s_ < 4; ++s_) {                                        \
            int wr_ = nt0 + s_ * 32 + srow;                                     \
            if (wr_ > nsz - 1) wr_ = nsz - 1;                                   \
            const u16* sb_ = W + (size_t)wr_ * lda + k0_ + slc * 8;             \
            GLOAD16(sb_, &Bls[BUF][(s_ * 256 + wid * 64) * 8]);                 \
        }                                                                       \
    } while (0)

    STAGE(0, it0);
    asm volatile("" ::: "memory");     // keep the two stage groups ordered
    STAGE(1, it0 + 1);
    // outstanding per thread: 16 (8 for it0, 8 for it0+1)

    for (int it = it0; it < it1; ++it) {
        const int cur = (it - it0) & 1;

        if (it + 1 < it1) {
            // wait for tile `it`'s 8 loads only; next tile's 8 stay in flight
            asm volatile("s_waitcnt vmcnt(8)\n\ts_barrier" ::: "memory");
        } else {
            asm volatile("s_waitcnt vmcnt(0)\n\ts_barrier" ::: "memory");
        }

        s16x8 af[4][2], bfv[4][2];
        #pragma unroll
        for (int mi = 0; mi < 4; ++mi)
            #pragma unroll
            for (int kc = 0; kc < 2; ++kc) {
                int row = wm + mi * 16 + li;
                int ch  = (kc * 4 + lg) ^ (row & 7);
                af[mi][kc] = *(const s16x8*)&Als[cur][row * 64 + ch * 8];
            }
        #pragma unroll
        for (int ni = 0; ni < 4; ++ni)
            #pragma unroll
            for (int kc = 0; kc < 2; ++kc) {
                int row = wn + ni * 16 + li;
                int ch  = (kc * 4 + lg) ^ (row & 7);
                bfv[ni][kc] = *(const s16x8*)&Bls[cur][row * 64 + ch * 8];
            }
        #pragma unroll
        for (int mi = 0; mi < 4; ++mi)
            #pragma unroll
            for (int ni = 0; ni < 4; ++ni)
                #pragma unroll
                for (int kc = 0; kc < 2; ++kc)
                    acc[mi][ni] = mfma_bf16(af[mi][kc], bfv[ni][kc], acc[mi][ni]);

        // all my ds_reads complete, then barrier: whole block done reading
        // buf[cur] -> safe to restage it. vmcnt NOT drained here.
        asm volatile("s_waitcnt lgkmcnt(0)\n\ts_barrier" ::: "memory");

        if (it + 2 < it1) STAGE(cur, it + 2);
    }
#undef STAGE

    #pragma unroll
    for (int ni = 0; ni < 4; ++ni) {
        int colr = nt0 + wn + ni * 16 + li;
        if (colr < nsz) {
            #pragma unroll
            for (int mi = 0; mi < 4; ++mi)
                #pragma unroll
                for (int r = 0; r < 4; ++r) {
                    int row = m0 + wm + mi * 16 + lg * 4 + r;
                    Cp[(size_t)row * ldc + cb + colr] = f2bf(acc[mi][ni][r]);
                }
        }
    }
}

// ---------------------------------------------------------------------------
// RoPE + bias + bf16 convert from 3 bf16 split-K partials.
// ---------------------------------------------------------------------------
__global__ void rope_kernel(const u16* __restrict__ qkvp,
                            const float* __restrict__ qb, const float* __restrict__ kb,
                            const float* __restrict__ vb,
                            u16* __restrict__ qo, u16* __restrict__ ko, u16* __restrict__ vo)
{
    const long long PST = 1024LL * 5120;
    int id = blockIdx.x * 256 + threadIdx.x;   // 1024 * 2560
    int s  = id / 2560;
    int r  = id % 2560;
    const u16* r0 = qkvp + (size_t)s * 5120;
    if (r < 2304) {
        bool isq = r < 2048;
        int rr   = isq ? r : r - 2048;
        int hh   = rr >> 5;
        int d    = rr & 31;
        int col  = (isq ? 0 : 4096) + hh * 64 + d;
        int bcol = isq ? col : col - 4096;
        const float* bias = isq ? qb : kb;
        float t1 = bf2f(r0[col])      + bf2f(r0[col + PST])      + bf2f(r0[col + 2 * PST])      + bias[bcol];
        float t2 = bf2f(r0[col + 32]) + bf2f(r0[col + 32 + PST]) + bf2f(r0[col + 32 + 2 * PST]) + bias[bcol + 32];
        // inv_freq = 150000^(-d/32) = exp2(-d * log2(150000)/32)
        float ang = (float)s * exp2f((float)d * -0.5373314f);
        float sn, cs;
        sincosf(ang, &sn, &cs);
        float sc = isq ? 0.125f : 1.0f;    // fold score scale HD^-0.5 into q
        float o1 = (t1 * cs - t2 * sn) * sc;
        float o2 = (t1 * sn + t2 * cs) * sc;
        u16* dst = isq ? qo : ko;
        int ldd  = isq ? 4096 : 512;
        dst[(size_t)s * ldd + bcol]      = f2bf(o1);
        dst[(size_t)s * ldd + bcol + 32] = f2bf(o2);
    } else {
        int e = (r - 2304) * 2;
        int c0 = 4608 + e;
        float v0 = bf2f(r0[c0])     + bf2f(r0[c0 + PST])     + bf2f(r0[c0 + 2 * PST])     + vb[e];
        float v1 = bf2f(r0[c0 + 1]) + bf2f(r0[c0 + 1 + PST]) + bf2f(r0[c0 + 1 + 2 * PST]) + vb[e + 1];
        vo[(size_t)s * 512 + e]     = f2bf(v0);
        vo[(size_t)s * 512 + e + 1] = f2bf(v1);
    }
}

// ---------------------------------------------------------------------------
// out = sum of 5 bf16 split-K partials + bias (fp32)
// ---------------------------------------------------------------------------
__global__ void reduce_out_kernel(const u16* __restrict__ parts,
                                  const float* __restrict__ bias,
                                  float* __restrict__ out)
{
    int id = blockIdx.x * 256 + threadIdx.x;      // 0..368639 (8-elem groups)
    const long long stride = 1024LL * 2880;
    long long base = (long long)id * 8;
    float s[8];
    #pragma unroll
    for (int j = 0; j < 8; ++j) s[j] = 0.f;
    #pragma unroll
    for (int p = 0; p < 5; ++p) {
        s16x8 v = *(const s16x8*)(parts + p * stride + base);
        #pragma unroll
        for (int j = 0; j < 8; ++j) s[j] += bf2f((u16)v[j]);
    }
    int cb = (int)(base % 2880);
    f32x4 b0 = *(const f32x4*)(bias + cb);
    f32x4 b1 = *(const f32x4*)(bias + cb + 4);
    f32x4 o0 = {s[0] + b0[0], s[1] + b0[1], s[2] + b0[2], s[3] + b0[3]};
    f32x4 o1 = {s[4] + b1[0], s[5] + b1[1], s[6] + b1[2], s[7] + b1[3]};
    *(f32x4*)(out + base)     = o0;
    *(f32x4*)(out + base + 4) = o1;
}

// ---------------------------------------------------------------------------
// Sliding-window GQA attention with sinks (unchanged, proven).
// ---------------------------------------------------------------------------
__global__ __launch_bounds__(256, 2) void attn_kernel(
    const u16* __restrict__ Q, const u16* __restrict__ Kb, const u16* __restrict__ Vb,
    const float* __restrict__ sinks, u16* __restrict__ Ob)
{
    __shared__ u16 Kls[64 * 64];
    __shared__ u16 Pls[4][16 * 72];

    const int h    = blockIdx.x;
    const int qblk = blockIdx.y;
    const int kvh  = h >> 3;
    const int tid  = threadIdx.x;
    const int lane = tid & 63;
    const int w    = tid >> 6;
    const int li   = lane & 15;
    const int lg   = lane >> 4;
    const int qw   = qblk * 64 + w * 16;

    s16x8 aq[2];
    {
        const u16* qrow = Q + ((size_t)(qw + li) * 64 + h) * 64 + lg * 8;
        aq[0] = *(const s16x8*)(qrow);
        aq[1] = *(const s16x8*)(qrow + 32);
    }

    const float snk = sinks[h];
    float m_run[4], l_run[4];
    f32x4 oacc[4];
    #pragma unroll
    for (int r = 0; r < 4; ++r) { m_run[r] = snk; l_run[r] = 1.0f; }
    #pragma unroll
    for (int ni = 0; ni < 4; ++ni) oacc[ni] = (f32x4){0.f, 0.f, 0.f, 0.f};

    const int srow = tid >> 3;
    const int slc  = (tid & 7) ^ (srow & 7);

    for (int t = 0; t < 3; ++t) {
        int jt = qblk - 2 + t;
        if (jt < 0) continue;
        int j0 = jt * 64;

        #pragma unroll
        for (int it = 0; it < 2; ++it) {
            const u16* src = Kb + ((size_t)(j0 + it * 32 + srow) * 8 + kvh) * 64 + slc * 8;
            GLOAD16(src, &Kls[(it * 256 + w * 64) * 8]);
        }
        __syncthreads();

        f32x4 sc[4];
        #pragma unroll
        for (int nf = 0; nf < 4; ++nf) {
            sc[nf] = (f32x4){0.f, 0.f, 0.f, 0.f};
            #pragma unroll
            for (int kc = 0; kc < 2; ++kc) {
                int row = nf * 16 + li;
                int ch  = (kc * 4 + lg) ^ (row & 7);
                s16x8 bk = *(const s16x8*)&Kls[row * 64 + ch * 8];
                sc[nf] = mfma_bf16(aq[kc], bk, sc[nf]);
            }
        }

        #pragma unroll
        for (int r = 0; r < 4; ++r) {
            const int qg = qw + lg * 4 + r;
            float mx = -1e30f;
            #pragma unroll
            for (int nf = 0; nf < 4; ++nf) {
                int jg = j0 + nf * 16 + li;
                bool ok = (jg <= qg) && (qg - jg < 128);
                float v = ok ? sc[nf][r] : -1e30f;
                sc[nf][r] = v;
                mx = fmaxf(mx, v);
            }
            #pragma unroll
            for (int off = 1; off < 16; off <<= 1)
                mx = fmaxf(mx, __shfl_xor(mx, off));
            float mnew = fmaxf(m_run[r], mx);
            float corr = __expf(m_run[r] - mnew);
            m_run[r] = mnew;
            float rs = 0.f;
            #pragma unroll
            for (int nf = 0; nf < 4; ++nf) {
                float p = __expf(sc[nf][r] - mnew);
                rs += p;
                Pls[w][(lg * 4 + r) * 72 + nf * 16 + li] = f2bf(p);
            }
            #pragma unroll
            for (int off = 1; off < 16; off <<= 1)
                rs += __shfl_xor(rs, off);
            l_run[r] = l_run[r] * corr + rs;
            #pragma unroll
            for (int ni = 0; ni < 4; ++ni) oacc[ni][r] *= corr;
        }
        __syncthreads();   // all K reads done; P writes drained

        #pragma unroll
        for (int kc = 0; kc < 2; ++kc) {
            s16x8 pa = *(const s16x8*)&Pls[w][li * 72 + kc * 32 + lg * 8];
            #pragma unroll
            for (int ni = 0; ni < 4; ++ni) {
                const u16* vsrc = Vb + ((size_t)(j0 + kc * 32 + lg * 8) * 8 + kvh) * 64 + ni * 16 + li;
                s16x8 bv;
                #pragma unroll
                for (int i = 0; i < 8; ++i) bv[i] = (short)vsrc[(size_t)i * 512];
                oacc[ni] = mfma_bf16(pa, bv, oacc[ni]);
            }
        }
    }

    #pragma unroll
    for (int r = 0; r < 4; ++r) {
        float inv = 1.0f / l_run[r];
        #pragma unroll
        for (int ni = 0; ni < 4; ++ni)
            Ob[((size_t)(qw + lg * 4 + r) * 64 + h) * 64 + ni * 16 + li] = f2bf(oacc[ni][r] * inv);
    }
}

// ---------------------------------------------------------------------------
extern "C" void kernel_launch(void* const* d_in, const int* in_sizes, int n_in,
                              void* d_out, int out_size, void* d_ws, size_t ws_size,
                              hipStream_t stream)
{
    const float* x     = (const float*)d_in[0];
    const float* wq_w  = (const float*)d_in[1];
    const float* wq_b  = (const float*)d_in[2];
    const float* wk_w  = (const float*)d_in[3];
    const float* wk_b  = (const float*)d_in[4];
    const float* wv_w  = (const float*)d_in[5];
    const float* wv_b  = (const float*)d_in[6];
    const float* wo_w  = (const float*)d_in[7];
    const float* wo_b  = (const float*)d_in[8];
    const float* sinks = (const float*)d_in[9];

    char* ws = (char*)d_ws;
    // Lifetimes / overlays (peak ~88.5 MB):
    //   [0, 35,389,440)   xb|wqb|wkb|wvb                (cvt1 -> gemm1)
    //       after rope overlays: qr@0|kr|vbf|attb       (rope -> gemm2)
    //   [35,389,440, 66,846,720)  qkvp 3 bf16 partials  (gemm1 -> rope)
    //       after rope overlays: wob@35,389,440         (cvt_wo -> gemm2)
    //   [58,982,400, 88,473,600)  oprt 5 bf16 partials  (gemm2 -> reduce)
    u16*   xb   = (u16*)(ws + 0);
    u16*   wqb  = (u16*)(ws + 5898240ULL);
    u16*   wkb  = (u16*)(ws + 29491200ULL);
    u16*   wvb  = (u16*)(ws + 32440320ULL);
    u16*   qkvp = (u16*)(ws + 35389440ULL);      // 3 bf16 partials, stride 1024*5120
    u16*   qr   = (u16*)(ws + 0);
    u16*   kr   = (u16*)(ws + 8388608ULL);
    u16*   vbf  = (u16*)(ws + 9437184ULL);
    u16*   attb = (u16*)(ws + 10485760ULL);
    u16*   wob  = (u16*)(ws + 35389440ULL);
    u16*   oprt = (u16*)(ws + 58982400ULL);      // 5 bf16 partials, stride 1024*2880

    (void)in_sizes; (void)n_in; (void)out_size; (void)ws_size;

    // 1) bf16 conversions (x, wq, wk, wv)
    cvt1_kernel<<<17280, 256, 0, stream>>>(x, wq_w, wk_w, wv_w, xb, wqb, wkb, wvb);
    // 2) fused QKV projection, split-K=3 -> 3 bf16 partials [1024][5120]
    gemm_bf16nt<<<dim3(320, 1, 3), 256, 0, stream>>>(xb, 2880, 45, 40,
        wqb, 32, 4096, 0,
        wkb, 4, 512, 4096,
        wvb, 4, 512, 4608,
        qkvp, 5120, 1024LL * 5120);
    // 3) RoPE + partial-sum + bias + convert (q pre-scaled by 0.125)
    rope_kernel<<<10240, 256, 0, stream>>>(qkvp, wq_b, wk_b, wv_b, qr, kr, vbf);
    // 4) wo -> bf16 (overlays dead qkv partials)
    cvt_wo_kernel<<<11520, 256, 0, stream>>>(wo_w, wob);
    // 5) attention -> attb bf16 [1024][4096]
    attn_kernel<<<dim3(64, 16), 256, 0, stream>>>(qr, kr, vbf, sinks, attb);
    // 6) output projection, split-K=5 -> 5 bf16 partials [1024][2880]
    gemm_bf16nt<<<dim3(192, 1, 5), 256, 0, stream>>>(attb, 4096, 64, 23,
        wob, 23, 2880, 0,
        wob, 0, 0, 0,
        wob, 0, 0, 0,
        oprt, 2880, 1024LL * 2880);
    // 7) reduce partials + bias -> d_out fp32 [1024][2880]
    reduce_out_kernel<<<1440, 256, 0, stream>>>(oprt, wo_b, (float*)d_out);
}

// Round 5
// 138.762 us; speedup vs baseline: 1.3163x; 1.0096x over previous
//
#include <hip/hip_runtime.h>

typedef __attribute__((ext_vector_type(4))) float f32x4;
typedef __attribute__((ext_vector_type(8))) short s16x8;
typedef unsigned short u16;

#define DEVI __device__ __forceinline__

// fp32 -> bf16 round-to-nearest-even
DEVI u16 f2bf(float f) {
    union { float f; unsigned int u; } v; v.f = f;
    unsigned int r = v.u + 0x7FFFu + ((v.u >> 16) & 1u);
    return (u16)(r >> 16);
}
DEVI float bf2f(u16 b) {
    union { unsigned int u; float f; } v; v.u = ((unsigned int)b) << 16;
    return v.f;
}

typedef __attribute__((address_space(1))) void gv_t;   // global
typedef __attribute__((address_space(3))) void sv_t;   // LDS

#define GLOAD16(SRC, DST) __builtin_amdgcn_global_load_lds( \
    (gv_t*)(SRC), (sv_t*)(DST), 16, 0, 0)

DEVI f32x4 mfma_bf16(s16x8 a, s16x8 b, f32x4 c) {
    return __builtin_amdgcn_mfma_f32_16x16x32_bf16(a, b, c, 0, 0, 0);
}

// ---------------------------------------------------------------------------
// fp32 -> bf16 conversion of x, wq, wk, wv, wo (one fused streaming pass)
// ---------------------------------------------------------------------------
__global__ void cvt_all_kernel(
    const float* __restrict__ x,  const float* __restrict__ wq, const float* __restrict__ wk,
    const float* __restrict__ wv, const float* __restrict__ wo,
    u16* __restrict__ xb, u16* __restrict__ wqb, u16* __restrict__ wkb,
    u16* __restrict__ wvb, u16* __restrict__ wob)
{
    int id = blockIdx.x * 256 + threadIdx.x;   // 0 .. 7372800-1 (f32x4 units)
    const float* s; u16* d; int off;
    if      (id < 737280)  { s = x;  d = xb;  off = id; }
    else if (id < 3686400) { s = wq; d = wqb; off = id - 737280; }
    else if (id < 4055040) { s = wk; d = wkb; off = id - 3686400; }
    else if (id < 4423680) { s = wv; d = wvb; off = id - 4055040; }
    else                   { s = wo; d = wob; off = id - 4423680; }
    f32x4 v = *(const f32x4*)(s + (size_t)off * 4);
    union { u16 u[4]; unsigned long long ll; } o;
    #pragma unroll
    for (int j = 0; j < 4; ++j) o.u[j] = f2bf(v[j]);
    *(unsigned long long*)(d + (size_t)off * 4) = o.ll;
}

// ---------------------------------------------------------------------------
// NT GEMM, split-K, depth-2 counted-vmcnt pipeline, 512-thread blocks.
// C_part[z] = A[M][K](bf16) * W[n][K](bf16)^T -> bf16 partials (no bias).
// 128x128 tile, BK=64, 8 waves of 64x32, 16x16x32 MFMA, gload_lds width 16,
// XOR chunk swizzle (proven 0-conflict), XCD-aware block mapping.
// 64 KB LDS -> 2 blocks/CU -> 16 waves/CU; vmcnt never drains to 0 in loop.
// ---------------------------------------------------------------------------
__global__ __launch_bounds__(512, 4) void gemm_bf16nt(
    const u16* __restrict__ A, int lda, int kit, int ntot,
    const u16* __restrict__ W0, int t0, int n0, int c0,
    const u16* __restrict__ W1, int t1, int n1, int c1,
    const u16* __restrict__ W2, int t2, int n2, int c2,
    u16* __restrict__ C, int ldc, long long cstride)
{
    __shared__ u16 Als[2][128 * 64];
    __shared__ u16 Bls[2][128 * 64];

    const int lin = blockIdx.x;
    const int xc  = lin & 7;
    const int mm  = lin >> 3;
    const int nbl = xc + 8 * (mm >> 3);
    const int yt  = mm & 7;
    if (nbl >= ntot) return;   // uniform per block; no barriers executed

    const int tid  = threadIdx.x;
    const int lane = tid & 63;
    const int wid  = tid >> 6;          // 0..7
    const int li   = lane & 15;
    const int lg   = lane >> 4;
    const int m0   = yt * 128;

    const u16* W; int nt0, nsz, cb;
    if (nbl < t0)           { W = W0; nt0 = nbl * 128;             nsz = n0; cb = c0; }
    else if (nbl < t0 + t1) { W = W1; nt0 = (nbl - t0) * 128;      nsz = n1; cb = c1; }
    else                    { W = W2; nt0 = (nbl - t0 - t1) * 128; nsz = n2; cb = c2; }

    const int z  = blockIdx.z;
    const int S  = gridDim.z;
    const int it0 = (z * kit) / S;
    const int it1 = ((z + 1) * kit) / S;    // ranges >= 12 everywhere here
    u16* Cp = C + (long long)z * cstride;

    const int wm = (wid >> 2) * 64;     // {0, 64}
    const int wn = (wid & 3) * 32;      // {0, 32, 64, 96}

    f32x4 acc[4][2];
    #pragma unroll
    for (int mi = 0; mi < 4; ++mi)
        #pragma unroll
        for (int ni = 0; ni < 2; ++ni)
            acc[mi][ni] = (f32x4){0.f, 0.f, 0.f, 0.f};

    // staging: 2 A-loads + 2 B-loads per thread per tile (4 outstanding/tile)
#define STAGE(BUF, IT)                                                          \
    do {                                                                        \
        int k0_ = (IT) * 64;                                                    \
        _Pragma("unroll")                                                       \
        for (int s_ = 0; s_ < 2; ++s_) {                                        \
            int g_   = s_ * 512 + tid;                                          \
            int row_ = g_ >> 3;                                                 \
            int cs_  = (tid & 7) ^ (row_ & 7);                                  \
            const u16* sa_ = A + (size_t)(m0 + row_) * lda + k0_ + cs_ * 8;     \
            GLOAD16(sa_, &Als[BUF][g_ * 8]);                                    \
        }                                                                       \
        _Pragma("unroll")                                                       \
        for (int s_ = 0; s_ < 2; ++s_) {                                        \
            int g_   = s_ * 512 + tid;                                          \
            int row_ = g_ >> 3;                                                 \
            int wr_  = nt0 + row_;                                              \
            if (wr_ > nsz - 1) wr_ = nsz - 1;  /* ragged-N clamp */             \
            int cs_  = (tid & 7) ^ (row_ & 7);                                  \
            const u16* sb_ = W + (size_t)wr_ * lda + k0_ + cs_ * 8;             \
            GLOAD16(sb_, &Bls[BUF][g_ * 8]);                                    \
        }                                                                       \
    } while (0)

    STAGE(0, it0);
    asm volatile("" ::: "memory");     // keep the two stage groups ordered
    STAGE(1, it0 + 1);
    // outstanding per thread: 8 (4 for it0, 4 for it0+1)

    for (int it = it0; it < it1; ++it) {
        const int cur = (it - it0) & 1;

        if (it + 1 < it1) {
            // wait for tile `it`'s 4 loads only; next tile's 4 stay in flight
            asm volatile("s_waitcnt vmcnt(4)\n\ts_barrier" ::: "memory");
        } else {
            asm volatile("s_waitcnt vmcnt(0)\n\ts_barrier" ::: "memory");
        }

        s16x8 af[4][2], bfv[2][2];
        #pragma unroll
        for (int mi = 0; mi < 4; ++mi)
            #pragma unroll
            for (int kc = 0; kc < 2; ++kc) {
                int row = wm + mi * 16 + li;
                int ch  = (kc * 4 + lg) ^ (row & 7);
                af[mi][kc] = *(const s16x8*)&Als[cur][row * 64 + ch * 8];
            }
        #pragma unroll
        for (int ni = 0; ni < 2; ++ni)
            #pragma unroll
            for (int kc = 0; kc < 2; ++kc) {
                int row = wn + ni * 16 + li;
                int ch  = (kc * 4 + lg) ^ (row & 7);
                bfv[ni][kc] = *(const s16x8*)&Bls[cur][row * 64 + ch * 8];
            }
        #pragma unroll
        for (int mi = 0; mi < 4; ++mi)
            #pragma unroll
            for (int ni = 0; ni < 2; ++ni)
                #pragma unroll
                for (int kc = 0; kc < 2; ++kc)
                    acc[mi][ni] = mfma_bf16(af[mi][kc], bfv[ni][kc], acc[mi][ni]);

        // all my ds_reads complete, then barrier: whole block done reading
        // buf[cur] -> safe to restage it. vmcnt NOT drained here.
        asm volatile("s_waitcnt lgkmcnt(0)\n\ts_barrier" ::: "memory");

        if (it + 2 < it1) STAGE(cur, it + 2);
    }
#undef STAGE

    #pragma unroll
    for (int ni = 0; ni < 2; ++ni) {
        int colr = nt0 + wn + ni * 16 + li;
        if (colr < nsz) {
            #pragma unroll
            for (int mi = 0; mi < 4; ++mi)
                #pragma unroll
                for (int r = 0; r < 4; ++r) {
                    int row = m0 + wm + mi * 16 + lg * 4 + r;
                    Cp[(size_t)row * ldc + cb + colr] = f2bf(acc[mi][ni][r]);
                }
        }
    }
}

// ---------------------------------------------------------------------------
// RoPE + bias + bf16 convert from 3 bf16 split-K partials.
// ---------------------------------------------------------------------------
__global__ void rope_kernel(const u16* __restrict__ qkvp,
                            const float* __restrict__ qb, const float* __restrict__ kb,
                            const float* __restrict__ vb,
                            u16* __restrict__ qo, u16* __restrict__ ko, u16* __restrict__ vo)
{
    const long long PST = 1024LL * 5120;
    int id = blockIdx.x * 256 + threadIdx.x;   // 1024 * 2560
    int s  = id / 2560;
    int r  = id % 2560;
    const u16* r0 = qkvp + (size_t)s * 5120;
    if (r < 2304) {
        bool isq = r < 2048;
        int rr   = isq ? r : r - 2048;
        int hh   = rr >> 5;
        int d    = rr & 31;
        int col  = (isq ? 0 : 4096) + hh * 64 + d;
        int bcol = isq ? col : col - 4096;
        const float* bias = isq ? qb : kb;
        float t1 = bf2f(r0[col])      + bf2f(r0[col + PST])      + bf2f(r0[col + 2 * PST])      + bias[bcol];
        float t2 = bf2f(r0[col + 32]) + bf2f(r0[col + 32 + PST]) + bf2f(r0[col + 32 + 2 * PST]) + bias[bcol + 32];
        // inv_freq = 150000^(-d/32) = exp2(-d * log2(150000)/32)
        float ang = (float)s * exp2f((float)d * -0.5373314f);
        float sn, cs;
        sincosf(ang, &sn, &cs);
        float sc = isq ? 0.125f : 1.0f;    // fold score scale HD^-0.5 into q
        float o1 = (t1 * cs - t2 * sn) * sc;
        float o2 = (t1 * sn + t2 * cs) * sc;
        u16* dst = isq ? qo : ko;
        int ldd  = isq ? 4096 : 512;
        dst[(size_t)s * ldd + bcol]      = f2bf(o1);
        dst[(size_t)s * ldd + bcol + 32] = f2bf(o2);
    } else {
        int e = (r - 2304) * 2;
        int c0 = 4608 + e;
        float v0 = bf2f(r0[c0])     + bf2f(r0[c0 + PST])     + bf2f(r0[c0 + 2 * PST])     + vb[e];
        float v1 = bf2f(r0[c0 + 1]) + bf2f(r0[c0 + 1 + PST]) + bf2f(r0[c0 + 1 + 2 * PST]) + vb[e + 1];
        vo[(size_t)s * 512 + e]     = f2bf(v0);
        vo[(size_t)s * 512 + e + 1] = f2bf(v1);
    }
}

// ---------------------------------------------------------------------------
// out = sum of 5 bf16 split-K partials + bias (fp32)
// ---------------------------------------------------------------------------
__global__ void reduce_out_kernel(const u16* __restrict__ parts,
                                  const float* __restrict__ bias,
                                  float* __restrict__ out)
{
    int id = blockIdx.x * 256 + threadIdx.x;      // 0..368639 (8-elem groups)
    const long long stride = 1024LL * 2880;
    long long base = (long long)id * 8;
    float s[8];
    #pragma unroll
    for (int j = 0; j < 8; ++j) s[j] = 0.f;
    #pragma unroll
    for (int p = 0; p < 5; ++p) {
        s16x8 v = *(const s16x8*)(parts + p * stride + base);
        #pragma unroll
        for (int j = 0; j < 8; ++j) s[j] += bf2f((u16)v[j]);
    }
    int cb = (int)(base % 2880);
    f32x4 b0 = *(const f32x4*)(bias + cb);
    f32x4 b1 = *(const f32x4*)(bias + cb + 4);
    f32x4 o0 = {s[0] + b0[0], s[1] + b0[1], s[2] + b0[2], s[3] + b0[3]};
    f32x4 o1 = {s[4] + b1[0], s[5] + b1[1], s[6] + b1[2], s[7] + b1[3]};
    *(f32x4*)(out + base)     = o0;
    *(f32x4*)(out + base + 4) = o1;
}

// ---------------------------------------------------------------------------
// Sliding-window GQA attention with sinks (unchanged, proven).
// ---------------------------------------------------------------------------
__global__ __launch_bounds__(256, 2) void attn_kernel(
    const u16* __restrict__ Q, const u16* __restrict__ Kb, const u16* __restrict__ Vb,
    const float* __restrict__ sinks, u16* __restrict__ Ob)
{
    __shared__ u16 Kls[64 * 64];
    __shared__ u16 Pls[4][16 * 72];

    const int h    = blockIdx.x;
    const int qblk = blockIdx.y;
    const int kvh  = h >> 3;
    const int tid  = threadIdx.x;
    const int lane = tid & 63;
    const int w    = tid >> 6;
    const int li   = lane & 15;
    const int lg   = lane >> 4;
    const int qw   = qblk * 64 + w * 16;

    s16x8 aq[2];
    {
        const u16* qrow = Q + ((size_t)(qw + li) * 64 + h) * 64 + lg * 8;
        aq[0] = *(const s16x8*)(qrow);
        aq[1] = *(const s16x8*)(qrow + 32);
    }

    const float snk = sinks[h];
    float m_run[4], l_run[4];
    f32x4 oacc[4];
    #pragma unroll
    for (int r = 0; r < 4; ++r) { m_run[r] = snk; l_run[r] = 1.0f; }
    #pragma unroll
    for (int ni = 0; ni < 4; ++ni) oacc[ni] = (f32x4){0.f, 0.f, 0.f, 0.f};

    const int srow = tid >> 3;
    const int slc  = (tid & 7) ^ (srow & 7);

    for (int t = 0; t < 3; ++t) {
        int jt = qblk - 2 + t;
        if (jt < 0) continue;
        int j0 = jt * 64;

        #pragma unroll
        for (int it = 0; it < 2; ++it) {
            const u16* src = Kb + ((size_t)(j0 + it * 32 + srow) * 8 + kvh) * 64 + slc * 8;
            GLOAD16(src, &Kls[(it * 256 + w * 64) * 8]);
        }
        __syncthreads();

        f32x4 sc[4];
        #pragma unroll
        for (int nf = 0; nf < 4; ++nf) {
            sc[nf] = (f32x4){0.f, 0.f, 0.f, 0.f};
            #pragma unroll
            for (int kc = 0; kc < 2; ++kc) {
                int row = nf * 16 + li;
                int ch  = (kc * 4 + lg) ^ (row & 7);
                s16x8 bk = *(const s16x8*)&Kls[row * 64 + ch * 8];
                sc[nf] = mfma_bf16(aq[kc], bk, sc[nf]);
            }
        }

        #pragma unroll
        for (int r = 0; r < 4; ++r) {
            const int qg = qw + lg * 4 + r;
            float mx = -1e30f;
            #pragma unroll
            for (int nf = 0; nf < 4; ++nf) {
                int jg = j0 + nf * 16 + li;
                bool ok = (jg <= qg) && (qg - jg < 128);
                float v = ok ? sc[nf][r] : -1e30f;
                sc[nf][r] = v;
                mx = fmaxf(mx, v);
            }
            #pragma unroll
            for (int off = 1; off < 16; off <<= 1)
                mx = fmaxf(mx, __shfl_xor(mx, off));
            float mnew = fmaxf(m_run[r], mx);
            float corr = __expf(m_run[r] - mnew);
            m_run[r] = mnew;
            float rs = 0.f;
            #pragma unroll
            for (int nf = 0; nf < 4; ++nf) {
                float p = __expf(sc[nf][r] - mnew);
                rs += p;
                Pls[w][(lg * 4 + r) * 72 + nf * 16 + li] = f2bf(p);
            }
            #pragma unroll
            for (int off = 1; off < 16; off <<= 1)
                rs += __shfl_xor(rs, off);
            l_run[r] = l_run[r] * corr + rs;
            #pragma unroll
            for (int ni = 0; ni < 4; ++ni) oacc[ni][r] *= corr;
        }
        __syncthreads();   // all K reads done; P writes drained

        #pragma unroll
        for (int kc = 0; kc < 2; ++kc) {
            s16x8 pa = *(const s16x8*)&Pls[w][li * 72 + kc * 32 + lg * 8];
            #pragma unroll
            for (int ni = 0; ni < 4; ++ni) {
                const u16* vsrc = Vb + ((size_t)(j0 + kc * 32 + lg * 8) * 8 + kvh) * 64 + ni * 16 + li;
                s16x8 bv;
                #pragma unroll
                for (int i = 0; i < 8; ++i) bv[i] = (short)vsrc[(size_t)i * 512];
                oacc[ni] = mfma_bf16(pa, bv, oacc[ni]);
            }
        }
    }

    #pragma unroll
    for (int r = 0; r < 4; ++r) {
        float inv = 1.0f / l_run[r];
        #pragma unroll
        for (int ni = 0; ni < 4; ++ni)
            Ob[((size_t)(qw + lg * 4 + r) * 64 + h) * 64 + ni * 16 + li] = f2bf(oacc[ni][r] * inv);
    }
}

// ---------------------------------------------------------------------------
extern "C" void kernel_launch(void* const* d_in, const int* in_sizes, int n_in,
                              void* d_out, int out_size, void* d_ws, size_t ws_size,
                              hipStream_t stream)
{
    const float* x     = (const float*)d_in[0];
    const float* wq_w  = (const float*)d_in[1];
    const float* wq_b  = (const float*)d_in[2];
    const float* wk_w  = (const float*)d_in[3];
    const float* wk_b  = (const float*)d_in[4];
    const float* wv_w  = (const float*)d_in[5];
    const float* wv_b  = (const float*)d_in[6];
    const float* wo_w  = (const float*)d_in[7];
    const float* wo_b  = (const float*)d_in[8];
    const float* sinks = (const float*)d_in[9];

    char* ws = (char*)d_ws;
    // Layout (peak 112.1 MB; 117.9 proven available in R2):
    //   [0, 35,389,440)           xb|wqb|wkb|wvb        (cvt -> gemm1)
    //       after rope overlays:  qr@0|kr|vbf|attb      (rope -> gemm2)
    //   [35,389,440, 66,846,720)  qkvp 3 bf16 partials  (gemm1 -> rope)
    //   [58,982,400, 88,473,600)  oprt 5 bf16 partials  (gemm2 -> reduce)
    //       (overlaps dead qkvp tail -- qkvp dead after rope)
    //   [88,473,600, 112,066,560) wob                   (cvt -> gemm2)
    u16*   xb   = (u16*)(ws + 0);
    u16*   wqb  = (u16*)(ws + 5898240ULL);
    u16*   wkb  = (u16*)(ws + 29491200ULL);
    u16*   wvb  = (u16*)(ws + 32440320ULL);
    u16*   qkvp = (u16*)(ws + 35389440ULL);      // 3 bf16 partials, stride 1024*5120
    u16*   qr   = (u16*)(ws + 0);
    u16*   kr   = (u16*)(ws + 8388608ULL);
    u16*   vbf  = (u16*)(ws + 9437184ULL);
    u16*   attb = (u16*)(ws + 10485760ULL);
    u16*   oprt = (u16*)(ws + 58982400ULL);      // 5 bf16 partials, stride 1024*2880
    u16*   wob  = (u16*)(ws + 88473600ULL);

    (void)in_sizes; (void)n_in; (void)out_size; (void)ws_size;

    // 1) bf16 conversions (x, wq, wk, wv, wo -- one pass)
    cvt_all_kernel<<<28800, 256, 0, stream>>>(x, wq_w, wk_w, wv_w, wo_w,
                                              xb, wqb, wkb, wvb, wob);
    // 2) fused QKV projection, split-K=3 -> 3 bf16 partials [1024][5120]
    gemm_bf16nt<<<dim3(320, 1, 3), 512, 0, stream>>>(xb, 2880, 45, 40,
        wqb, 32, 4096, 0,
        wkb, 4, 512, 4096,
        wvb, 4, 512, 4608,
        qkvp, 5120, 1024LL * 5120);
    // 3) RoPE + partial-sum + bias + convert (q pre-scaled by 0.125)
    rope_kernel<<<10240, 256, 0, stream>>>(qkvp, wq_b, wk_b, wv_b, qr, kr, vbf);
    // 4) attention -> attb bf16 [1024][4096]
    attn_kernel<<<dim3(64, 16), 256, 0, stream>>>(qr, kr, vbf, sinks, attb);
    // 5) output projection, split-K=5 -> 5 bf16 partials [1024][2880]
    gemm_bf16nt<<<dim3(192, 1, 5), 512, 0, stream>>>(attb, 4096, 64, 23,
        wob, 23, 2880, 0,
        wob, 0, 0, 0,
        wob, 0, 0, 0,
        oprt, 2880, 1024LL * 2880);
    // 6) reduce partials + bias -> d_out fp32 [1024][2880]
    reduce_out_kernel<<<1440, 256, 0, stream>>>(oprt, wo_b, (float*)d_out);
}